// Round 2
// baseline (799.598 us; speedup 1.0000x reference)
//
#include <hip/hip_runtime.h>
#include <hip/hip_fp16.h>
#include <stdint.h>

#define IN_F   4096
#define OUT_F  4096
#define M_ROWS 8192
#define BM 128
#define BN 128
#define BK 32

typedef _Float16 v8h __attribute__((ext_vector_type(8)));
typedef float    v4f __attribute__((ext_vector_type(4)));

// ---------------- Kernel 1: dequant 3-bit groups -> f16 weight [OUT_F][IN_F] ----------------
// Harness passes uint8 data widened to int32 (one int per original byte) and
// f16 data widened to f32. Each group: 12 bytes = little-endian 3-bit stream
// of 32 values. val = norm*(2q-7)/7.
__global__ void dequant_kernel(const int* __restrict__ q,
                               const float* __restrict__ norm,
                               _Float16* __restrict__ w) {
    int g = blockIdx.x * blockDim.x + threadIdx.x;   // 524288 groups
    const int4* p = (const int4*)(q + (size_t)g * 12);  // 48 B per group, 16B aligned
    int4 q0 = p[0], q1 = p[1], q2 = p[2];
    uint32_t b[12] = {(uint32_t)q0.x, (uint32_t)q0.y, (uint32_t)q0.z, (uint32_t)q0.w,
                      (uint32_t)q1.x, (uint32_t)q1.y, (uint32_t)q1.z, (uint32_t)q1.w,
                      (uint32_t)q2.x, (uint32_t)q2.y, (uint32_t)q2.z, (uint32_t)q2.w};
    uint64_t lo = 0, hi = 0;
#pragma unroll
    for (int i = 0; i < 8; ++i) lo |= (uint64_t)(b[i] & 0xff) << (8 * i);      // stream bits 0..63
#pragma unroll
    for (int i = 0; i < 8; ++i) hi |= (uint64_t)(b[4 + i] & 0xff) << (8 * i);  // stream bits 32..95
    float nrm = norm[g];
    float scale = nrm * (2.0f / 7.0f);
    v8h out[4];
#pragma unroll
    for (int i = 0; i < 32; ++i) {
        int p3 = 3 * i;
        uint32_t qv = (i <= 20) ? (uint32_t)((lo >> p3) & 7)
                                : (uint32_t)((hi >> (p3 - 32)) & 7);
        float v = fmaf((float)qv, scale, -nrm);   // (q/7)*2*norm - norm
        out[i >> 3][i & 7] = (_Float16)v;
    }
    v8h* dst = (v8h*)(w + (size_t)g * 32);
    dst[0] = out[0]; dst[1] = out[1]; dst[2] = out[2]; dst[3] = out[3];
}

// ---------------- Kernel 2: cast x f32 -> f16 ----------------
__global__ void castx_kernel(const float* __restrict__ x, _Float16* __restrict__ o) {
    size_t i = ((size_t)blockIdx.x * blockDim.x + threadIdx.x) * 8;
    float4 a = *(const float4*)(x + i);
    float4 b = *(const float4*)(x + i + 4);
    v8h r;
    r[0] = (_Float16)a.x; r[1] = (_Float16)a.y; r[2] = (_Float16)a.z; r[3] = (_Float16)a.w;
    r[4] = (_Float16)b.x; r[5] = (_Float16)b.y; r[6] = (_Float16)b.z; r[7] = (_Float16)b.w;
    *(v8h*)(o + i) = r;
}

// ---------------- Kernel 3: GEMM C[M,N] = A[M,K] * B[N,K]^T + bias ----------------
// 128x128 tile, BK=32, 256 threads (4 waves in 2x2), each wave 4x4 tiles of 16x16x32 MFMA.
// LDS layout: [kb(0..3)][row(0..127)][8 halves] -- contiguous in exactly the order
// global_load_lds lanes write (wave-uniform base + lane*16), and fragment ds_read_b128
// addresses are consecutive 16B across the 16 lanes of a quad (conflict-free).
__global__ void __launch_bounds__(256)
gemm_kernel(const _Float16* __restrict__ A,   // [M_ROWS][IN_F]
            const _Float16* __restrict__ B,   // [OUT_F][IN_F]  (dequant w, row = n)
            const float* __restrict__ bias,   // [OUT_F] (f32, harness-widened)
            float* __restrict__ C) {          // [M_ROWS][OUT_F]
    __shared__ __align__(16) _Float16 As[4 * BM * 8];  // 8 KB
    __shared__ __align__(16) _Float16 Bs[4 * BN * 8];  // 8 KB

    const int GRID_N = OUT_F / BN;   // 32
    const int GROUP_M = 8;
    int pid = blockIdx.x;
    int group = pid / (GROUP_M * GRID_N);
    int first_m = group * GROUP_M;
    int pid_in = pid % (GROUP_M * GRID_N);
    int pm = first_m + (pid_in % GROUP_M);
    int pn = pid_in / GROUP_M;

    const int m0 = pm * BM, n0 = pn * BN;

    int t = threadIdx.x;
    int lane = t & 63, wid = t >> 6;
    int wm = wid >> 1, wn = wid & 1;

    // staging: 512 slots of 16B per tile; slot s -> kb = s>>7, row = s&127
    int s0 = t, s1 = t + 256;
    int kb0 = s0 >> 7, r0 = s0 & 127;
    int kb1 = s1 >> 7, r1 = s1 & 127;

    const _Float16* Ag0 = A + (size_t)(m0 + r0) * IN_F + kb0 * 8;
    const _Float16* Ag1 = A + (size_t)(m0 + r1) * IN_F + kb1 * 8;
    const _Float16* Bg0 = B + (size_t)(n0 + r0) * IN_F + kb0 * 8;
    const _Float16* Bg1 = B + (size_t)(n0 + r1) * IN_F + kb1 * 8;

    v4f acc[4][4] = {};

    const int quad = lane >> 4, lr = lane & 15;

    for (int k0 = 0; k0 < IN_F; k0 += BK) {
        __syncthreads();
        __builtin_amdgcn_global_load_lds(
            (const __attribute__((address_space(1))) void*)(Ag0 + k0),
            (__attribute__((address_space(3))) void*)(As + s0 * 8), 16, 0, 0);
        __builtin_amdgcn_global_load_lds(
            (const __attribute__((address_space(1))) void*)(Ag1 + k0),
            (__attribute__((address_space(3))) void*)(As + s1 * 8), 16, 0, 0);
        __builtin_amdgcn_global_load_lds(
            (const __attribute__((address_space(1))) void*)(Bg0 + k0),
            (__attribute__((address_space(3))) void*)(Bs + s0 * 8), 16, 0, 0);
        __builtin_amdgcn_global_load_lds(
            (const __attribute__((address_space(1))) void*)(Bg1 + k0),
            (__attribute__((address_space(3))) void*)(Bs + s1 * 8), 16, 0, 0);
        __syncthreads();

        v8h a[4], b[4];
#pragma unroll
        for (int i = 0; i < 4; ++i)
            a[i] = *(const v8h*)&As[(quad * BM + wm * 64 + i * 16 + lr) * 8];
#pragma unroll
        for (int j = 0; j < 4; ++j)
            b[j] = *(const v8h*)&Bs[(quad * BN + wn * 64 + j * 16 + lr) * 8];
#pragma unroll
        for (int i = 0; i < 4; ++i)
#pragma unroll
            for (int j = 0; j < 4; ++j)
                acc[i][j] = __builtin_amdgcn_mfma_f32_16x16x32_f16(a[i], b[j], acc[i][j], 0, 0, 0);
    }

    // Epilogue: C/D layout col = lane&15, row = quad*4 + reg
#pragma unroll
    for (int j = 0; j < 4; ++j) {
        int n = n0 + wn * 64 + j * 16 + lr;
        float bf = bias[n];
#pragma unroll
        for (int i = 0; i < 4; ++i) {
            int mrow = m0 + wm * 64 + i * 16 + quad * 4;
#pragma unroll
            for (int rr = 0; rr < 4; ++rr)
                C[(size_t)(mrow + rr) * OUT_F + n] = acc[i][j][rr] + bf;
        }
    }
}

extern "C" void kernel_launch(void* const* d_in, const int* in_sizes, int n_in,
                              void* d_out, int out_size, void* d_ws, size_t ws_size,
                              hipStream_t stream) {
    (void)in_sizes; (void)n_in; (void)out_size; (void)ws_size;
    const float* x    = (const float*)d_in[0];
    const int*   wq   = (const int*)d_in[1];     // [524288][12] bytes, widened to int32
    const float* wnrm = (const float*)d_in[2];   // [524288]  (f16 widened to f32)
    const float* bias = (const float*)d_in[3];   // [4096]    (f16 widened to f32)
    float* out = (float*)d_out;

    _Float16* w16 = (_Float16*)d_ws;                                     // 32 MB
    _Float16* x16 = (_Float16*)((char*)d_ws + (size_t)OUT_F * IN_F * 2); // 64 MB

    const int NUM_GROUPS = OUT_F * IN_F / 32;  // 524288
    dequant_kernel<<<NUM_GROUPS / 256, 256, 0, stream>>>(wq, wnrm, w16);
    castx_kernel<<<(size_t)M_ROWS * IN_F / 8 / 256, 256, 0, stream>>>(x, x16);

    int grid = (M_ROWS / BM) * (OUT_F / BN);   // 2048
    gemm_kernel<<<grid, 256, 0, stream>>>(x16, w16, bias, out);
}

// Round 3
// 791.679 us; speedup vs baseline: 1.0100x; 1.0100x over previous
//
#include <hip/hip_runtime.h>
#include <hip/hip_fp16.h>
#include <stdint.h>

#define IN_F   4096
#define OUT_F  4096
#define M_ROWS 8192
#define BM 128
#define BN 128
#define BK 32

typedef _Float16 v8h __attribute__((ext_vector_type(8)));
typedef float    v4f __attribute__((ext_vector_type(4)));

// ---------------- Kernel 1: dequant 3-bit groups -> f16 weight [OUT_F][IN_F] ----------------
// Harness passes uint8 data widened to int32 (one int per original byte) and
// f16 data widened to f32. Each group: 12 bytes = little-endian 3-bit stream
// of 32 values. val = norm*(2q-7)/7.
__global__ void dequant_kernel(const int* __restrict__ q,
                               const float* __restrict__ norm,
                               _Float16* __restrict__ w) {
    int g = blockIdx.x * blockDim.x + threadIdx.x;   // 524288 groups
    const int4* p = (const int4*)(q + (size_t)g * 12);  // 48 B per group, 16B aligned
    int4 q0 = p[0], q1 = p[1], q2 = p[2];
    uint32_t b[12] = {(uint32_t)q0.x, (uint32_t)q0.y, (uint32_t)q0.z, (uint32_t)q0.w,
                      (uint32_t)q1.x, (uint32_t)q1.y, (uint32_t)q1.z, (uint32_t)q1.w,
                      (uint32_t)q2.x, (uint32_t)q2.y, (uint32_t)q2.z, (uint32_t)q2.w};
    uint64_t lo = 0, hi = 0;
#pragma unroll
    for (int i = 0; i < 8; ++i) lo |= (uint64_t)(b[i] & 0xff) << (8 * i);      // stream bits 0..63
#pragma unroll
    for (int i = 0; i < 8; ++i) hi |= (uint64_t)(b[4 + i] & 0xff) << (8 * i);  // stream bits 32..95
    float nrm = norm[g];
    float scale = nrm * (2.0f / 7.0f);
    v8h out[4];
#pragma unroll
    for (int i = 0; i < 32; ++i) {
        int p3 = 3 * i;
        uint32_t qv = (i <= 20) ? (uint32_t)((lo >> p3) & 7)
                                : (uint32_t)((hi >> (p3 - 32)) & 7);
        float v = fmaf((float)qv, scale, -nrm);   // (q/7)*2*norm - norm
        out[i >> 3][i & 7] = (_Float16)v;
    }
    v8h* dst = (v8h*)(w + (size_t)g * 32);
    dst[0] = out[0]; dst[1] = out[1]; dst[2] = out[2]; dst[3] = out[3];
}

// ---------------- Kernel 2: cast x f32 -> f16 ----------------
__global__ void castx_kernel(const float* __restrict__ x, _Float16* __restrict__ o) {
    size_t i = ((size_t)blockIdx.x * blockDim.x + threadIdx.x) * 8;
    float4 a = *(const float4*)(x + i);
    float4 b = *(const float4*)(x + i + 4);
    v8h r;
    r[0] = (_Float16)a.x; r[1] = (_Float16)a.y; r[2] = (_Float16)a.z; r[3] = (_Float16)a.w;
    r[4] = (_Float16)b.x; r[5] = (_Float16)b.y; r[6] = (_Float16)b.z; r[7] = (_Float16)b.w;
    *(v8h*)(o + i) = r;
}

// ---------------- Kernel 3: GEMM C[M,N] = A[M,K] * B[N,K]^T + bias ----------------
// 128x128 tile, BK=32, 256 threads (4 waves 2x2), each wave 4x4 tiles of 16x16x32 MFMA.
// DOUBLE-BUFFERED LDS, one barrier per iter: loads for tile k+1 are issued right
// after the barrier, so the compiler's vmcnt(0) drain at the NEXT barrier happens
// after a full compute phase has hidden the global->LDS latency.
// LDS layout per buffer: [kb(0..3)][row(0..127)][8 halves] -- contiguous in the
// exact order global_load_lds lanes write (wave-uniform base + lane*16); fragment
// ds_read_b128 addresses are consecutive 16B across a quad's 16 lanes (conflict-free).
__global__ void __launch_bounds__(256)
gemm_kernel(const _Float16* __restrict__ A,   // [M_ROWS][IN_F]
            const _Float16* __restrict__ B,   // [OUT_F][IN_F]  (dequant w, row = n)
            const float* __restrict__ bias,   // [OUT_F] (f32, harness-widened)
            float* __restrict__ C) {          // [M_ROWS][OUT_F]
    __shared__ __align__(16) _Float16 As[2][4 * BM * 8];  // 2 x 8 KB
    __shared__ __align__(16) _Float16 Bs[2][4 * BN * 8];  // 2 x 8 KB

    const int GRID_N = OUT_F / BN;   // 32
    const int GROUP_M = 8;
    int pid = blockIdx.x;
    int group = pid / (GROUP_M * GRID_N);
    int first_m = group * GROUP_M;
    int pid_in = pid % (GROUP_M * GRID_N);
    int pm = first_m + (pid_in % GROUP_M);
    int pn = pid_in / GROUP_M;

    const int m0 = pm * BM, n0 = pn * BN;

    int t = threadIdx.x;
    int lane = t & 63, wid = t >> 6;
    int wm = wid >> 1, wn = wid & 1;

    // staging: 512 slots of 16B per tile; slot s -> kb = s>>7, row = s&127
    int s0 = t, s1 = t + 256;
    int kb0 = s0 >> 7, r0 = s0 & 127;
    int kb1 = s1 >> 7, r1 = s1 & 127;

    const _Float16* Ag0 = A + (size_t)(m0 + r0) * IN_F + kb0 * 8;
    const _Float16* Ag1 = A + (size_t)(m0 + r1) * IN_F + kb1 * 8;
    const _Float16* Bg0 = B + (size_t)(n0 + r0) * IN_F + kb0 * 8;
    const _Float16* Bg1 = B + (size_t)(n0 + r1) * IN_F + kb1 * 8;

    v4f acc[4][4] = {};
    const int quad = lane >> 4, lr = lane & 15;

#define STAGE(buf, k0)                                                              \
    do {                                                                            \
        __builtin_amdgcn_global_load_lds(                                           \
            (const __attribute__((address_space(1))) void*)(Ag0 + (k0)),            \
            (__attribute__((address_space(3))) void*)(&As[buf][s0 * 8]), 16, 0, 0); \
        __builtin_amdgcn_global_load_lds(                                           \
            (const __attribute__((address_space(1))) void*)(Ag1 + (k0)),            \
            (__attribute__((address_space(3))) void*)(&As[buf][s1 * 8]), 16, 0, 0); \
        __builtin_amdgcn_global_load_lds(                                           \
            (const __attribute__((address_space(1))) void*)(Bg0 + (k0)),            \
            (__attribute__((address_space(3))) void*)(&Bs[buf][s0 * 8]), 16, 0, 0); \
        __builtin_amdgcn_global_load_lds(                                           \
            (const __attribute__((address_space(1))) void*)(Bg1 + (k0)),            \
            (__attribute__((address_space(3))) void*)(&Bs[buf][s1 * 8]), 16, 0, 0); \
    } while (0)

    const int NT = IN_F / BK;   // 128 K-tiles
    STAGE(0, 0);                // prefetch tile 0

    for (int kt = 0; kt < NT; ++kt) {
        int cur = kt & 1;
        __syncthreads();        // drains tile kt's loads (they flew during tile kt-1's compute)
        if (kt + 1 < NT) STAGE(cur ^ 1, (kt + 1) * BK);

        v8h a[4], b[4];
#pragma unroll
        for (int i = 0; i < 4; ++i)
            a[i] = *(const v8h*)&As[cur][(quad * BM + wm * 64 + i * 16 + lr) * 8];
#pragma unroll
        for (int j = 0; j < 4; ++j)
            b[j] = *(const v8h*)&Bs[cur][(quad * BN + wn * 64 + j * 16 + lr) * 8];
#pragma unroll
        for (int i = 0; i < 4; ++i)
#pragma unroll
            for (int j = 0; j < 4; ++j)
                acc[i][j] = __builtin_amdgcn_mfma_f32_16x16x32_f16(a[i], b[j], acc[i][j], 0, 0, 0);
    }
#undef STAGE

    // Epilogue: C/D layout col = lane&15, row = quad*4 + reg
#pragma unroll
    for (int j = 0; j < 4; ++j) {
        int n = n0 + wn * 64 + j * 16 + lr;
        float bf = bias[n];
#pragma unroll
        for (int i = 0; i < 4; ++i) {
            int mrow = m0 + wm * 64 + i * 16 + quad * 4;
#pragma unroll
            for (int rr = 0; rr < 4; ++rr)
                C[(size_t)(mrow + rr) * OUT_F + n] = acc[i][j][rr] + bf;
        }
    }
}

extern "C" void kernel_launch(void* const* d_in, const int* in_sizes, int n_in,
                              void* d_out, int out_size, void* d_ws, size_t ws_size,
                              hipStream_t stream) {
    (void)in_sizes; (void)n_in; (void)out_size; (void)ws_size;
    const float* x    = (const float*)d_in[0];
    const int*   wq   = (const int*)d_in[1];     // [524288][12] bytes, widened to int32
    const float* wnrm = (const float*)d_in[2];   // [524288]  (f16 widened to f32)
    const float* bias = (const float*)d_in[3];   // [4096]    (f16 widened to f32)
    float* out = (float*)d_out;

    _Float16* w16 = (_Float16*)d_ws;                                     // 32 MB
    _Float16* x16 = (_Float16*)((char*)d_ws + (size_t)OUT_F * IN_F * 2); // 64 MB

    const int NUM_GROUPS = OUT_F * IN_F / 32;  // 524288
    dequant_kernel<<<NUM_GROUPS / 256, 256, 0, stream>>>(wq, wnrm, w16);
    castx_kernel<<<(size_t)M_ROWS * IN_F / 8 / 256, 256, 0, stream>>>(x, x16);

    int grid = (M_ROWS / BM) * (OUT_F / BN);   // 2048
    gemm_kernel<<<grid, 256, 0, stream>>>(x16, w16, bias, out);
}

// Round 4
// 749.971 us; speedup vs baseline: 1.0662x; 1.0556x over previous
//
#include <hip/hip_runtime.h>
#include <hip/hip_fp16.h>
#include <stdint.h>

#define IN_F   4096
#define OUT_F  4096
#define M_ROWS 8192
#define BM 128
#define BN 128
#define BK 32

typedef _Float16 v8h __attribute__((ext_vector_type(8)));
typedef float    v4f __attribute__((ext_vector_type(4)));

// ---------------- Kernel 1: dequant 3-bit groups -> f16 weight [OUT_F][IN_F] ----------------
__global__ void dequant_kernel(const int* __restrict__ q,
                               const float* __restrict__ norm,
                               _Float16* __restrict__ w) {
    int g = blockIdx.x * blockDim.x + threadIdx.x;   // 524288 groups
    const int4* p = (const int4*)(q + (size_t)g * 12);  // 48 B per group (int-widened bytes)
    int4 q0 = p[0], q1 = p[1], q2 = p[2];
    uint32_t b[12] = {(uint32_t)q0.x, (uint32_t)q0.y, (uint32_t)q0.z, (uint32_t)q0.w,
                      (uint32_t)q1.x, (uint32_t)q1.y, (uint32_t)q1.z, (uint32_t)q1.w,
                      (uint32_t)q2.x, (uint32_t)q2.y, (uint32_t)q2.z, (uint32_t)q2.w};
    uint64_t lo = 0, hi = 0;
#pragma unroll
    for (int i = 0; i < 8; ++i) lo |= (uint64_t)(b[i] & 0xff) << (8 * i);      // stream bits 0..63
#pragma unroll
    for (int i = 0; i < 8; ++i) hi |= (uint64_t)(b[4 + i] & 0xff) << (8 * i);  // stream bits 32..95
    float nrm = norm[g];
    float scale = nrm * (2.0f / 7.0f);
    v8h out[4];
#pragma unroll
    for (int i = 0; i < 32; ++i) {
        int p3 = 3 * i;
        uint32_t qv = (i <= 20) ? (uint32_t)((lo >> p3) & 7)
                                : (uint32_t)((hi >> (p3 - 32)) & 7);
        float v = fmaf((float)qv, scale, -nrm);   // (q/7)*2*norm - norm
        out[i >> 3][i & 7] = (_Float16)v;
    }
    v8h* dst = (v8h*)(w + (size_t)g * 32);
    dst[0] = out[0]; dst[1] = out[1]; dst[2] = out[2]; dst[3] = out[3];
}

// ---------------- Kernel 2: cast x f32 -> f16 ----------------
__global__ void castx_kernel(const float* __restrict__ x, _Float16* __restrict__ o) {
    size_t i = ((size_t)blockIdx.x * blockDim.x + threadIdx.x) * 8;
    float4 a = *(const float4*)(x + i);
    float4 b = *(const float4*)(x + i + 4);
    v8h r;
    r[0] = (_Float16)a.x; r[1] = (_Float16)a.y; r[2] = (_Float16)a.z; r[3] = (_Float16)a.w;
    r[4] = (_Float16)b.x; r[5] = (_Float16)b.y; r[6] = (_Float16)b.z; r[7] = (_Float16)b.w;
    *(v8h*)(o + i) = r;
}

// ---------------- Kernel 3: GEMM C[M,N] = A[M,K] * B[N,K]^T + bias ----------------
// 128x128 tile, BK=32, 256 threads (4 waves 2x2), wave does 4x4 tiles of 16x16x32 MFMA.
// RASTER block order: pn = pid & 31. XCD = pid % 8 (round-robin), 32 == 0 mod 8, so each
// XCD sees pn in {c, c+8, c+16, c+24}: a fixed 4 MB B working set, exactly L2-resident.
// DOUBLE-BUFFERED LDS, manually unrolled x2 so the buffer index is compile-time constant
// (R3's dynamic index bloated VALU 7%->33%). One barrier per K-tile; each staged load has
// a full compute phase in flight before the barrier's vmcnt(0) drain.
__global__ void __launch_bounds__(256)
gemm_kernel(const _Float16* __restrict__ A,   // [M_ROWS][IN_F]
            const _Float16* __restrict__ B,   // [OUT_F][IN_F]  (dequant w, row = n)
            const float* __restrict__ bias,   // [OUT_F]
            float* __restrict__ C) {          // [M_ROWS][OUT_F]
    __shared__ __align__(16) _Float16 As0[4 * BM * 8];  // 8 KB each
    __shared__ __align__(16) _Float16 As1[4 * BM * 8];
    __shared__ __align__(16) _Float16 Bs0[4 * BN * 8];
    __shared__ __align__(16) _Float16 Bs1[4 * BN * 8];

    const int GRID_N = OUT_F / BN;   // 32
    int pid = blockIdx.x;
    int pm = pid >> 5;               // raster: M-major
    int pn = pid & (GRID_N - 1);

    const int m0 = pm * BM, n0 = pn * BN;

    int t = threadIdx.x;
    int lane = t & 63, wid = t >> 6;
    int wm = wid >> 1, wn = wid & 1;

    // staging: 512 slots of 16B per tile; slot s -> kb = s>>7, row = s&127
    int s0 = t, s1 = t + 256;
    int kb0 = s0 >> 7, r0 = s0 & 127;
    int kb1 = s1 >> 7, r1 = s1 & 127;

    const _Float16* Ag0 = A + (size_t)(m0 + r0) * IN_F + kb0 * 8;
    const _Float16* Ag1 = A + (size_t)(m0 + r1) * IN_F + kb1 * 8;
    const _Float16* Bg0 = B + (size_t)(n0 + r0) * IN_F + kb0 * 8;
    const _Float16* Bg1 = B + (size_t)(n0 + r1) * IN_F + kb1 * 8;

    v4f acc[4][4] = {};
    const int quad = lane >> 4, lr = lane & 15;

#define STAGE(Abuf, Bbuf, k0)                                                      \
    do {                                                                           \
        __builtin_amdgcn_global_load_lds(                                          \
            (const __attribute__((address_space(1))) void*)(Ag0 + (k0)),           \
            (__attribute__((address_space(3))) void*)(&Abuf[s0 * 8]), 16, 0, 0);   \
        __builtin_amdgcn_global_load_lds(                                          \
            (const __attribute__((address_space(1))) void*)(Ag1 + (k0)),           \
            (__attribute__((address_space(3))) void*)(&Abuf[s1 * 8]), 16, 0, 0);   \
        __builtin_amdgcn_global_load_lds(                                          \
            (const __attribute__((address_space(1))) void*)(Bg0 + (k0)),           \
            (__attribute__((address_space(3))) void*)(&Bbuf[s0 * 8]), 16, 0, 0);   \
        __builtin_amdgcn_global_load_lds(                                          \
            (const __attribute__((address_space(1))) void*)(Bg1 + (k0)),           \
            (__attribute__((address_space(3))) void*)(&Bbuf[s1 * 8]), 16, 0, 0);   \
    } while (0)

#define COMPUTE(Abuf, Bbuf)                                                        \
    do {                                                                           \
        v8h a[4], b[4];                                                            \
        _Pragma("unroll")                                                          \
        for (int i = 0; i < 4; ++i)                                                \
            a[i] = *(const v8h*)&Abuf[(quad * BM + wm * 64 + i * 16 + lr) * 8];    \
        _Pragma("unroll")                                                          \
        for (int j = 0; j < 4; ++j)                                                \
            b[j] = *(const v8h*)&Bbuf[(quad * BN + wn * 64 + j * 16 + lr) * 8];    \
        _Pragma("unroll")                                                          \
        for (int i = 0; i < 4; ++i)                                                \
            _Pragma("unroll")                                                      \
            for (int j = 0; j < 4; ++j)                                            \
                acc[i][j] = __builtin_amdgcn_mfma_f32_16x16x32_f16(a[i], b[j],     \
                                                                   acc[i][j], 0, 0, 0); \
    } while (0)

    const int NT = IN_F / BK;   // 128 K-tiles (even)
    STAGE(As0, Bs0, 0);

    for (int kt = 0; kt < NT; kt += 2) {
        __syncthreads();                                   // drains buf0 loads
        STAGE(As1, Bs1, (kt + 1) * BK);                    // kt+1 <= 127 always
        COMPUTE(As0, Bs0);
        __syncthreads();                                   // drains buf1 loads
        if (kt + 2 < NT) STAGE(As0, Bs0, (kt + 2) * BK);
        COMPUTE(As1, Bs1);
    }
#undef STAGE
#undef COMPUTE

    // Epilogue: C/D layout col = lane&15, row = quad*4 + reg
#pragma unroll
    for (int j = 0; j < 4; ++j) {
        int n = n0 + wn * 64 + j * 16 + lr;
        float bf = bias[n];
#pragma unroll
        for (int i = 0; i < 4; ++i) {
            int mrow = m0 + wm * 64 + i * 16 + quad * 4;
#pragma unroll
            for (int rr = 0; rr < 4; ++rr)
                C[(size_t)(mrow + rr) * OUT_F + n] = acc[i][j][rr] + bf;
        }
    }
}

extern "C" void kernel_launch(void* const* d_in, const int* in_sizes, int n_in,
                              void* d_out, int out_size, void* d_ws, size_t ws_size,
                              hipStream_t stream) {
    (void)in_sizes; (void)n_in; (void)out_size; (void)ws_size;
    const float* x    = (const float*)d_in[0];
    const int*   wq   = (const int*)d_in[1];     // [524288][12] bytes, widened to int32
    const float* wnrm = (const float*)d_in[2];   // [524288]  (f16 widened to f32)
    const float* bias = (const float*)d_in[3];   // [4096]    (f16 widened to f32)
    float* out = (float*)d_out;

    _Float16* w16 = (_Float16*)d_ws;                                     // 32 MB
    _Float16* x16 = (_Float16*)((char*)d_ws + (size_t)OUT_F * IN_F * 2); // 64 MB

    const int NUM_GROUPS = OUT_F * IN_F / 32;  // 524288
    dequant_kernel<<<NUM_GROUPS / 256, 256, 0, stream>>>(wq, wnrm, w16);
    castx_kernel<<<(size_t)M_ROWS * IN_F / 8 / 256, 256, 0, stream>>>(x, x16);

    int grid = (M_ROWS / BM) * (OUT_F / BN);   // 2048
    gemm_kernel<<<grid, 256, 0, stream>>>(x16, w16, bias, out);
}